// Round 1
// baseline (181.051 us; speedup 1.0000x reference)
//
#include <hip/hip_runtime.h>
#include <hip/hip_bf16.h>
#include <cstdint>
#include <cstddef>

// Problem constants: B=1, S=2048, D=1024, H=16, d=64, W=64
#define S_LEN 2048
#define D_MODEL 1024
#define N_HEADS 16
#define H_DIM 64

typedef __attribute__((ext_vector_type(8))) short short8;
typedef __attribute__((ext_vector_type(4))) float f32x4;

__device__ __forceinline__ unsigned short f2bf(float f) {
  union { float f; uint32_t u; } c; c.f = f;
  uint32_t u = c.u;
  u += 0x7fffu + ((u >> 16) & 1u);
  return (unsigned short)(u >> 16);
}
__device__ __forceinline__ float bf2f(unsigned short b) {
  union { uint32_t u; float f; } c; c.u = ((uint32_t)b) << 16;
  return c.f;
}

__device__ __forceinline__ void gload16(const void* g, void* l) {
  __builtin_amdgcn_global_load_lds(
      (const __attribute__((address_space(1))) uint32_t*)g,
      (__attribute__((address_space(3))) uint32_t*)l, 16, 0, 0);
}

// ---------------- f32 -> bf16 convert (vectorized x4) ----------------
__global__ __launch_bounds__(256) void cvt_kernel(const float* __restrict__ src,
                                                  unsigned short* __restrict__ dst,
                                                  int n4) {
  int i = blockIdx.x * 256 + threadIdx.x;
  if (i >= n4) return;
  float4 v = reinterpret_cast<const float4*>(src)[i];
  ushort4 o;
  o.x = f2bf(v.x); o.y = f2bf(v.y); o.z = f2bf(v.z); o.w = f2bf(v.w);
  reinterpret_cast<ushort4*>(dst)[i] = o;
}

// ---------------- fused QKV projection GEMM ----------------
// out[m,n] = sum_k A[m,k] * W[n,k] + bias[n]
// A: [2048][1024] bf16, W: [1024][1024] bf16 (row = output feature)
// grid: (24, 16): x&7 = n-tile, x>>3 = which (0=q,1=k,2=v); y = m-tile
__global__ __launch_bounds__(256) void qkv_gemm(
    const unsigned short* __restrict__ Aq, const unsigned short* __restrict__ Ak,
    const unsigned short* __restrict__ Av,
    const unsigned short* __restrict__ Wq, const unsigned short* __restrict__ Wk,
    const unsigned short* __restrict__ Wv,
    const float* __restrict__ bq, const float* __restrict__ bk,
    const float* __restrict__ bv,
    float* __restrict__ Oq, float* __restrict__ Ok,
    unsigned short* __restrict__ Ov) {
  __shared__ __align__(16) unsigned short As[128][32];
  __shared__ __align__(16) unsigned short Bs[128][32];
  const int tid = threadIdx.x;
  const int w = tid >> 6, l = tid & 63;
  const int which = blockIdx.x >> 3;
  const int n0 = (blockIdx.x & 7) * 128;
  const int m0 = blockIdx.y * 128;
  const unsigned short* A = which == 0 ? Aq : which == 1 ? Ak : Av;
  const unsigned short* W = which == 0 ? Wq : which == 1 ? Wk : Wv;

  f32x4 acc[4][4];
#pragma unroll
  for (int a = 0; a < 4; ++a)
#pragma unroll
    for (int b = 0; b < 4; ++b) acc[a][b] = (f32x4){0.f, 0.f, 0.f, 0.f};

  const int wm = w >> 1, wn = w & 1;
  const int lr = l & 15, kq = l >> 4;
  const int srow = tid >> 2;          // staging row (issue 0), +64 for issue 1
  const int scol = (tid & 3) * 8;     // staging col (bf16 elems)

  for (int kt = 0; kt < 32; ++kt) {
    const int k0 = kt * 32;
    __syncthreads();
    gload16(A + (size_t)(m0 + srow) * 1024 + k0 + scol, (char*)As + tid * 16);
    gload16(A + (size_t)(m0 + 64 + srow) * 1024 + k0 + scol, (char*)As + 4096 + tid * 16);
    gload16(W + (size_t)(n0 + srow) * 1024 + k0 + scol, (char*)Bs + tid * 16);
    gload16(W + (size_t)(n0 + 64 + srow) * 1024 + k0 + scol, (char*)Bs + 4096 + tid * 16);
    __syncthreads();
    short8 af[4], bf[4];
#pragma unroll
    for (int f = 0; f < 4; ++f) {
      af[f] = *reinterpret_cast<const short8*>(&As[wm * 64 + f * 16 + lr][kq * 8]);
      bf[f] = *reinterpret_cast<const short8*>(&Bs[wn * 64 + f * 16 + lr][kq * 8]);
    }
#pragma unroll
    for (int fm = 0; fm < 4; ++fm)
#pragma unroll
      for (int fn = 0; fn < 4; ++fn)
        acc[fm][fn] = __builtin_amdgcn_mfma_f32_16x16x32_bf16(af[fm], bf[fn], acc[fm][fn], 0, 0, 0);
  }

  const float* bias = which == 0 ? bq : which == 1 ? bk : bv;
  if (which < 2) {
    float* Out = which == 0 ? Oq : Ok;
#pragma unroll
    for (int fm = 0; fm < 4; ++fm) {
      const int rbase = m0 + wm * 64 + fm * 16 + kq * 4;
#pragma unroll
      for (int fn = 0; fn < 4; ++fn) {
        const int c = n0 + wn * 64 + fn * 16 + lr;
        const float bb = bias[c];
#pragma unroll
        for (int j = 0; j < 4; ++j)
          Out[(size_t)(rbase + j) * 1024 + c] = acc[fm][fn][j] + bb;
      }
    }
  } else {
#pragma unroll
    for (int fm = 0; fm < 4; ++fm) {
      const int rbase = m0 + wm * 64 + fm * 16 + kq * 4;
#pragma unroll
      for (int fn = 0; fn < 4; ++fn) {
        const int c = n0 + wn * 64 + fn * 16 + lr;
        const float bb = bias[c];
#pragma unroll
        for (int j = 0; j < 4; ++j)
          Ov[(size_t)(rbase + j) * 1024 + c] = f2bf(acc[fm][fn][j] + bb);
      }
    }
  }
}

// ---------------- output projection GEMM ----------------
__global__ __launch_bounds__(256) void oproj_gemm(
    const unsigned short* __restrict__ A, const unsigned short* __restrict__ W,
    const float* __restrict__ bias, float* __restrict__ Out) {
  __shared__ __align__(16) unsigned short As[128][32];
  __shared__ __align__(16) unsigned short Bs[128][32];
  const int tid = threadIdx.x;
  const int w = tid >> 6, l = tid & 63;
  const int n0 = blockIdx.x * 128;
  const int m0 = blockIdx.y * 128;

  f32x4 acc[4][4];
#pragma unroll
  for (int a = 0; a < 4; ++a)
#pragma unroll
    for (int b = 0; b < 4; ++b) acc[a][b] = (f32x4){0.f, 0.f, 0.f, 0.f};

  const int wm = w >> 1, wn = w & 1;
  const int lr = l & 15, kq = l >> 4;
  const int srow = tid >> 2;
  const int scol = (tid & 3) * 8;

  for (int kt = 0; kt < 32; ++kt) {
    const int k0 = kt * 32;
    __syncthreads();
    gload16(A + (size_t)(m0 + srow) * 1024 + k0 + scol, (char*)As + tid * 16);
    gload16(A + (size_t)(m0 + 64 + srow) * 1024 + k0 + scol, (char*)As + 4096 + tid * 16);
    gload16(W + (size_t)(n0 + srow) * 1024 + k0 + scol, (char*)Bs + tid * 16);
    gload16(W + (size_t)(n0 + 64 + srow) * 1024 + k0 + scol, (char*)Bs + 4096 + tid * 16);
    __syncthreads();
    short8 af[4], bf[4];
#pragma unroll
    for (int f = 0; f < 4; ++f) {
      af[f] = *reinterpret_cast<const short8*>(&As[wm * 64 + f * 16 + lr][kq * 8]);
      bf[f] = *reinterpret_cast<const short8*>(&Bs[wn * 64 + f * 16 + lr][kq * 8]);
    }
#pragma unroll
    for (int fm = 0; fm < 4; ++fm)
#pragma unroll
      for (int fn = 0; fn < 4; ++fn)
        acc[fm][fn] = __builtin_amdgcn_mfma_f32_16x16x32_bf16(af[fm], bf[fn], acc[fm][fn], 0, 0, 0);
  }

#pragma unroll
  for (int fm = 0; fm < 4; ++fm) {
    const int rbase = m0 + wm * 64 + fm * 16 + kq * 4;
#pragma unroll
    for (int fn = 0; fn < 4; ++fn) {
      const int c = n0 + wn * 64 + fn * 16 + lr;
      const float bb = bias[c];
#pragma unroll
      for (int j = 0; j < 4; ++j)
        Out[(size_t)(rbase + j) * 1024 + c] = acc[fm][fn][j] + bb;
    }
  }
}

// ---------------- RoPE (in place), q also scaled by 1/8 ----------------
__global__ __launch_bounds__(256) void rope_kernel(float* __restrict__ q,
                                                   float* __restrict__ k) {
  int idx = blockIdx.x * 256 + threadIdx.x;  // 2048*16*32 = 1048576 threads
  int t = idx & 31;
  int h = (idx >> 5) & 15;
  int s = idx >> 9;
  // freq = 10000^(-t/32) = exp2(-t * log2(10000)/32)
  float freq = exp2f(-(float)t * 0.41524101186092f);
  float ang = (float)s * freq;
  float c = cosf(ang), sn = sinf(ang);
  int base = s * 1024 + h * 64 + t;
  float q1 = q[base], q2 = q[base + 32];
  q[base]      = (q1 * c - q2 * sn) * 0.125f;
  q[base + 32] = (q1 * sn + q2 * c) * 0.125f;
  float k1 = k[base], k2 = k[base + 32];
  k[base]      = k1 * c - k2 * sn;
  k[base + 32] = k1 * sn + k2 * c;
}

// ---------------- sliding-window attention ----------------
// one wave per (head, query pos). Lane j: score for key pos i-64+j (j<64);
// diagonal (offset 0) via all-lane butterfly reduce. Then softmax + PV.
__global__ __launch_bounds__(256) void swa_kernel(
    const float* __restrict__ q, const float* __restrict__ k,
    const unsigned short* __restrict__ v, unsigned short* __restrict__ ctx) {
  __shared__ float q_lds[4][64];
  __shared__ float p_lds[4][64];
  const int w = threadIdx.x >> 6, l = threadIdx.x & 63;
  const int i = blockIdx.x >> 2;            // query position
  const int h = (blockIdx.x & 3) * 4 + w;   // head

  const int hb = h * 64;
  float qv = q[(size_t)i * 1024 + hb + l];
  q_lds[w][l] = qv;

  // diagonal score: dot(q_i, k_i) across lanes
  float sd = qv * k[(size_t)i * 1024 + hb + l];
#pragma unroll
  for (int off = 32; off; off >>= 1) sd += __shfl_xor(sd, off);

  __syncthreads();

  const int jpos = i - 64 + l;
  float s = -INFINITY;
  if (jpos >= 0) {
    const float4* kr = reinterpret_cast<const float4*>(k + (size_t)jpos * 1024 + hb);
    const float4* ql4 = reinterpret_cast<const float4*>(q_lds[w]);
    float a0 = 0.f;
#pragma unroll
    for (int t4 = 0; t4 < 16; ++t4) {
      float4 kv = kr[t4];
      float4 qq = ql4[t4];
      a0 += qq.x * kv.x + qq.y * kv.y + qq.z * kv.z + qq.w * kv.w;
    }
    s = a0;
  }

  float mm = s;
#pragma unroll
  for (int off = 32; off; off >>= 1) mm = fmaxf(mm, __shfl_xor(mm, off));
  mm = fmaxf(mm, sd);

  float e = (jpos >= 0) ? __expf(s - mm) : 0.f;
  float ed = __expf(sd - mm);
  float den = e;
#pragma unroll
  for (int off = 32; off; off >>= 1) den += __shfl_xor(den, off);
  den += ed;
  float inv = 1.f / den;
  p_lds[w][l] = e * inv;
  float pd = ed * inv;

  __syncthreads();

  // PV: lane t accumulates ctx[t]
  float acc = pd * bf2f(v[(size_t)i * 1024 + hb + l]);
  const unsigned short* vcol = v + hb + l;
  const int j0 = (i >= 64) ? 0 : (64 - i);
  for (int j = j0; j < 64; ++j)
    acc += p_lds[w][j] * bf2f(vcol[(size_t)(i - 64 + j) * 1024]);

  ctx[(size_t)i * 1024 + hb + l] = f2bf(acc);
}

extern "C" void kernel_launch(void* const* d_in, const int* in_sizes, int n_in,
                              void* d_out, int out_size, void* d_ws, size_t ws_size,
                              hipStream_t stream) {
  const float* query = (const float*)d_in[0];
  const float* key   = (const float*)d_in[1];
  const float* value = (const float*)d_in[2];
  const float* q_w = (const float*)d_in[3];
  const float* q_b = (const float*)d_in[4];
  const float* k_w = (const float*)d_in[5];
  const float* k_b = (const float*)d_in[6];
  const float* v_w = (const float*)d_in[7];
  const float* v_b = (const float*)d_in[8];
  const float* o_w = (const float*)d_in[9];
  const float* o_b = (const float*)d_in[10];
  float* out = (float*)d_out;

  char* ws = (char*)d_ws;
  unsigned short* qbf = (unsigned short*)ws;   // inputs bf16: 3 x 2M elems
  unsigned short* kbf = qbf + 2097152;
  unsigned short* vbf = kbf + 2097152;
  unsigned short* wqb = vbf + 2097152;         // weights bf16: 4 x 1M elems
  unsigned short* wkb = wqb + 1048576;
  unsigned short* wvb = wkb + 1048576;
  unsigned short* wob = wvb + 1048576;
  float* qproj = (float*)(wob + 1048576);      // f32: 2M
  float* kproj = qproj + 2097152;              // f32: 2M
  unsigned short* vproj = (unsigned short*)(kproj + 2097152);  // bf16: 2M
  unsigned short* ctxb = vproj + 2097152;      // bf16: 2M
  // total ws use: ~46.1 MB

  cvt_kernel<<<2048, 256, 0, stream>>>(query, qbf, 524288);
  cvt_kernel<<<2048, 256, 0, stream>>>(key,   kbf, 524288);
  cvt_kernel<<<2048, 256, 0, stream>>>(value, vbf, 524288);
  cvt_kernel<<<1024, 256, 0, stream>>>(q_w, wqb, 262144);
  cvt_kernel<<<1024, 256, 0, stream>>>(k_w, wkb, 262144);
  cvt_kernel<<<1024, 256, 0, stream>>>(v_w, wvb, 262144);
  cvt_kernel<<<1024, 256, 0, stream>>>(o_w, wob, 262144);

  qkv_gemm<<<dim3(24, 16), 256, 0, stream>>>(qbf, kbf, vbf, wqb, wkb, wvb,
                                             q_b, k_b, v_b, qproj, kproj, vproj);
  rope_kernel<<<4096, 256, 0, stream>>>(qproj, kproj);
  swa_kernel<<<8192, 256, 0, stream>>>(qproj, kproj, vproj, ctxb);
  oproj_gemm<<<dim3(8, 16), 256, 0, stream>>>(ctxb, wob, o_b, out);
}

// Round 2
// 73.718 us; speedup vs baseline: 2.4560x; 2.4560x over previous
//
#include <hip/hip_runtime.h>
#include <hip/hip_bf16.h>
#include <cstdint>
#include <cstddef>

// B=1, S=2048, D=1024, H=16, d=64, W=64
typedef __attribute__((ext_vector_type(8))) short short8;
typedef __attribute__((ext_vector_type(4))) float f32x4;

__device__ __forceinline__ unsigned short f2bf(float f) {
  union { float f; uint32_t u; } c; c.f = f;
  uint32_t u = c.u;
  u += 0x7fffu + ((u >> 16) & 1u);
  return (unsigned short)(u >> 16);
}

__device__ __forceinline__ void gload16(const void* g, void* l) {
  __builtin_amdgcn_global_load_lds(
      (const __attribute__((address_space(1))) uint32_t*)g,
      (__attribute__((address_space(3))) uint32_t*)l, 16, 0, 0);
}

// ---------------- unified f32 -> bf16 convert ----------------
// segments (float4 units): 3 inputs x 524288, 4 weights x 262144 = 2621440
__global__ __launch_bounds__(256) void cvt_all(
    const float* __restrict__ q, const float* __restrict__ k, const float* __restrict__ v,
    const float* __restrict__ qw, const float* __restrict__ kw,
    const float* __restrict__ vw, const float* __restrict__ ow,
    unsigned short* __restrict__ qb, unsigned short* __restrict__ kb,
    unsigned short* __restrict__ vb, unsigned short* __restrict__ wqb,
    unsigned short* __restrict__ wkb, unsigned short* __restrict__ wvb,
    unsigned short* __restrict__ wob) {
  int i = blockIdx.x * 256 + threadIdx.x;
  const float* src; unsigned short* dst; int off;
  if (i < 1572864) {
    int seg = i >> 19; off = i & 524287;
    src = seg == 0 ? q : seg == 1 ? k : v;
    dst = seg == 0 ? qb : seg == 1 ? kb : vb;
  } else {
    int t = i - 1572864;
    int seg = t >> 18; off = t & 262143;
    src = seg == 0 ? qw : seg == 1 ? kw : seg == 2 ? vw : ow;
    dst = seg == 0 ? wqb : seg == 1 ? wkb : seg == 2 ? wvb : wob;
  }
  float4 x = reinterpret_cast<const float4*>(src)[off];
  ushort4 o;
  o.x = f2bf(x.x); o.y = f2bf(x.y); o.z = f2bf(x.z); o.w = f2bf(x.w);
  reinterpret_cast<ushort4*>(dst)[off] = o;
}

// ---------------- fused QKV GEMM + RoPE + V-transpose ----------------
// out = A @ W^T + b.  BM=128, BN=64, BK=32. 4 waves, per-wave 32x64.
// grid: x in [0,48): which = x>>4, n0 = (x&15)*64 (head-aligned); y: m0 = y*128
// which 0: q -> rope(q)*0.125 bf16 [2048][1024]
// which 1: k -> rope(k)       bf16 [2048][1024]
// which 2: v -> vT            bf16 [1024][2048]  (transposed)
__global__ __launch_bounds__(256) void qkv_gemm(
    const unsigned short* __restrict__ Aq, const unsigned short* __restrict__ Ak,
    const unsigned short* __restrict__ Av,
    const unsigned short* __restrict__ Wq, const unsigned short* __restrict__ Wk,
    const unsigned short* __restrict__ Wv,
    const float* __restrict__ bq, const float* __restrict__ bk,
    const float* __restrict__ bv,
    unsigned short* __restrict__ Oq, unsigned short* __restrict__ Ok,
    unsigned short* __restrict__ OvT) {
  __shared__ __align__(16) unsigned short As[128][32];
  __shared__ __align__(16) unsigned short Bs[64][32];
  const int tid = threadIdx.x;
  const int w = tid >> 6, l = tid & 63;
  const int which = blockIdx.x >> 4;
  const int n0 = (blockIdx.x & 15) * 64;
  const int m0 = blockIdx.y * 128;
  const unsigned short* A = which == 0 ? Aq : which == 1 ? Ak : Av;
  const unsigned short* W = which == 0 ? Wq : which == 1 ? Wk : Wv;

  f32x4 acc[2][4];
#pragma unroll
  for (int a = 0; a < 2; ++a)
#pragma unroll
    for (int b = 0; b < 4; ++b) acc[a][b] = (f32x4){0.f, 0.f, 0.f, 0.f};

  const int lr = l & 15, kq = l >> 4;
  const int srow = tid >> 2;       // 0..63
  const int scol = (tid & 3) * 8;

  for (int kt = 0; kt < 32; ++kt) {
    const int k0 = kt * 32;
    __syncthreads();
    gload16(A + (size_t)(m0 + srow) * 1024 + k0 + scol, (char*)As + tid * 16);
    gload16(A + (size_t)(m0 + 64 + srow) * 1024 + k0 + scol, (char*)As + 4096 + tid * 16);
    gload16(W + (size_t)(n0 + srow) * 1024 + k0 + scol, (char*)Bs + tid * 16);
    __syncthreads();
    short8 af[2], bf[4];
#pragma unroll
    for (int f = 0; f < 2; ++f)
      af[f] = *reinterpret_cast<const short8*>(&As[w * 32 + f * 16 + lr][kq * 8]);
#pragma unroll
    for (int f = 0; f < 4; ++f)
      bf[f] = *reinterpret_cast<const short8*>(&Bs[f * 16 + lr][kq * 8]);
#pragma unroll
    for (int fm = 0; fm < 2; ++fm)
#pragma unroll
      for (int fn = 0; fn < 4; ++fn)
        acc[fm][fn] = __builtin_amdgcn_mfma_f32_16x16x32_bf16(af[fm], bf[fn], acc[fm][fn], 0, 0, 0);
  }

  const float* bias = which == 0 ? bq : which == 1 ? bk : bv;
  if (which < 2) {
    // RoPE: c = n0 + fn*16 + lr; head-dim hd = fn*16+lr; pair (fn, fn+2).
    unsigned short* Out = which == 0 ? Oq : Ok;
    const float sc = which == 0 ? 0.125f : 1.0f;
#pragma unroll
    for (int fn = 0; fn < 2; ++fn) {
      const int c1 = n0 + fn * 16 + lr;
      const int c2 = c1 + 32;
      const int t = fn * 16 + lr;  // 0..31
      const float freq = exp2f(-(float)t * 0.415241012f);  // 10000^(-t/32)
      const float b1 = bias[c1], b2 = bias[c2];
#pragma unroll
      for (int fm = 0; fm < 2; ++fm) {
        const int rbase = m0 + w * 32 + fm * 16 + kq * 4;
#pragma unroll
        for (int j = 0; j < 4; ++j) {
          const int s = rbase + j;
          float sn, cs;
          __sincosf((float)s * freq, &sn, &cs);
          const float x1 = acc[fm][fn][j] + b1;
          const float x2 = acc[fm][fn + 2][j] + b2;
          Out[(size_t)s * 1024 + c1] = f2bf((x1 * cs - x2 * sn) * sc);
          Out[(size_t)s * 1024 + c2] = f2bf((x1 * sn + x2 * cs) * sc);
        }
      }
    }
  } else {
    // V transposed: OvT[c][row], pack 4 consecutive rows (8B stores)
#pragma unroll
    for (int fn = 0; fn < 4; ++fn) {
      const int c = n0 + fn * 16 + lr;
      const float bb = bias[c];
#pragma unroll
      for (int fm = 0; fm < 2; ++fm) {
        const int rbase = m0 + w * 32 + fm * 16 + kq * 4;
        ushort4 o;
        o.x = f2bf(acc[fm][fn][0] + bb);
        o.y = f2bf(acc[fm][fn][1] + bb);
        o.z = f2bf(acc[fm][fn][2] + bb);
        o.w = f2bf(acc[fm][fn][3] + bb);
        *reinterpret_cast<ushort4*>(OvT + (size_t)c * 2048 + rbase) = o;
      }
    }
  }
}

// ---------------- MFMA sliding-window attention ----------------
// block = (head h, 64-query tile qb). 4 waves; wave w owns queries i0+w*16..+15.
// Key span: [i0-64, i0+64). S = Q K^T (4x8 16x16 tiles per wave), band mask,
// row softmax in-register, P -> swizzled LDS -> A-fragments, ctx = P V.
__global__ __launch_bounds__(256) void attn_kernel(
    const unsigned short* __restrict__ qr, const unsigned short* __restrict__ kr,
    const unsigned short* __restrict__ vT, unsigned short* __restrict__ ctx) {
  __shared__ __align__(16) unsigned short Ps[4][16][128];  // 16KB, XOR-swizzled
  const int w = threadIdx.x >> 6, l = threadIdx.x & 63;
  const int h = blockIdx.x & 15, qb = blockIdx.x >> 4;
  const int i0 = qb * 64, hb = h * 64;
  const int r = l & 15, g = l >> 4;

  // Q fragments: row = i0 + w*16 + r, k-slice = kk*32 + g*8
  short8 qf[2];
#pragma unroll
  for (int kk = 0; kk < 2; ++kk)
    qf[kk] = *reinterpret_cast<const short8*>(
        qr + (size_t)(i0 + w * 16 + r) * 1024 + hb + kk * 32 + g * 8);

  // S = Q K^T over 8 key tiles
  f32x4 acc[8];
#pragma unroll
  for (int nt = 0; nt < 8; ++nt) acc[nt] = (f32x4){0.f, 0.f, 0.f, 0.f};
#pragma unroll
  for (int nt = 0; nt < 8; ++nt) {
    int kpos = i0 - 64 + nt * 16 + r;
    int krow = kpos < 0 ? 0 : kpos;
    const unsigned short* kp = kr + (size_t)krow * 1024 + hb + g * 8;
    short8 kf0 = *reinterpret_cast<const short8*>(kp);
    short8 kf1 = *reinterpret_cast<const short8*>(kp + 32);
    acc[nt] = __builtin_amdgcn_mfma_f32_16x16x32_bf16(qf[0], kf0, acc[nt], 0, 0, 0);
    acc[nt] = __builtin_amdgcn_mfma_f32_16x16x32_bf16(qf[1], kf1, acc[nt], 0, 0, 0);
  }

  // band mask + row softmax; D layout: col=lane&15 (key), row=g*4+j (query)
#pragma unroll
  for (int j = 0; j < 4; ++j) {
    const int iq = w * 16 + g * 4 + j;        // query within 64-block
    const int i = i0 + iq;                    // absolute query pos
    float sv[8];
    float m = -1e30f;
#pragma unroll
    for (int nt = 0; nt < 8; ++nt) {
      const int rel = nt * 16 + r - iq;       // kpos - (i-64), valid in [0,64]
      const int kpos = i0 - 64 + nt * 16 + r;
      const bool ok = (rel >= 0) && (rel <= 64) && (kpos >= 0);
      sv[nt] = ok ? acc[nt][j] : -1e30f;
      m = fmaxf(m, sv[nt]);
    }
#pragma unroll
    for (int off = 8; off; off >>= 1) m = fmaxf(m, __shfl_xor(m, off));
    float e[8], den = 0.f;
#pragma unroll
    for (int nt = 0; nt < 8; ++nt) { e[nt] = __expf(sv[nt] - m); den += e[nt]; }
#pragma unroll
    for (int off = 8; off; off >>= 1) den += __shfl_xor(den, off);
    const float inv = 1.f / den;
    const int qrow = g * 4 + j;
    const int sw = (qrow & 7) << 3;
#pragma unroll
    for (int nt = 0; nt < 8; ++nt)
      Ps[w][qrow][(nt * 16 + r) ^ sw] = f2bf(e[nt] * inv);
  }

  __syncthreads();

  // P as A-fragments: row = r (query), k-slice = kk*32 + g*8 (key)
  short8 pf[4];
  const int swr = (r & 7) << 3;
#pragma unroll
  for (int kk = 0; kk < 4; ++kk)
    pf[kk] = *reinterpret_cast<const short8*>(&Ps[w][r][(kk * 32 + g * 8) ^ swr]);

  // ctx = P V: B-fragments from vT (row = dim, k-contiguous keys)
  f32x4 co[4];
#pragma unroll
  for (int n = 0; n < 4; ++n) co[n] = (f32x4){0.f, 0.f, 0.f, 0.f};
#pragma unroll
  for (int kk = 0; kk < 4; ++kk) {
    int cb = i0 - 64 + kk * 32 + g * 8;
    if (cb < 0) cb = 0;  // P is 0 on masked keys; clamped reads stay finite
#pragma unroll
    for (int n = 0; n < 4; ++n) {
      short8 vf = *reinterpret_cast<const short8*>(
          vT + (size_t)(hb + n * 16 + r) * 2048 + cb);
      co[n] = __builtin_amdgcn_mfma_f32_16x16x32_bf16(pf[kk], vf, co[n], 0, 0, 0);
    }
  }

  // write ctx bf16 [2048][1024]: col = hb + n*16 + r, row = i0 + w*16 + g*4 + j
#pragma unroll
  for (int n = 0; n < 4; ++n)
#pragma unroll
    for (int j = 0; j < 4; ++j)
      ctx[(size_t)(i0 + w * 16 + g * 4 + j) * 1024 + hb + n * 16 + r] = f2bf(co[n][j]);
}

// ---------------- output projection GEMM ----------------
// BM=128, BN=64: grid (16,16) = 256 blocks
__global__ __launch_bounds__(256) void oproj_gemm(
    const unsigned short* __restrict__ A, const unsigned short* __restrict__ W,
    const float* __restrict__ bias, float* __restrict__ Out) {
  __shared__ __align__(16) unsigned short As[128][32];
  __shared__ __align__(16) unsigned short Bs[64][32];
  const int tid = threadIdx.x;
  const int w = tid >> 6, l = tid & 63;
  const int n0 = blockIdx.x * 64;
  const int m0 = blockIdx.y * 128;

  f32x4 acc[2][4];
#pragma unroll
  for (int a = 0; a < 2; ++a)
#pragma unroll
    for (int b = 0; b < 4; ++b) acc[a][b] = (f32x4){0.f, 0.f, 0.f, 0.f};

  const int lr = l & 15, kq = l >> 4;
  const int srow = tid >> 2;
  const int scol = (tid & 3) * 8;

  for (int kt = 0; kt < 32; ++kt) {
    const int k0 = kt * 32;
    __syncthreads();
    gload16(A + (size_t)(m0 + srow) * 1024 + k0 + scol, (char*)As + tid * 16);
    gload16(A + (size_t)(m0 + 64 + srow) * 1024 + k0 + scol, (char*)As + 4096 + tid * 16);
    gload16(W + (size_t)(n0 + srow) * 1024 + k0 + scol, (char*)Bs + tid * 16);
    __syncthreads();
    short8 af[2], bf[4];
#pragma unroll
    for (int f = 0; f < 2; ++f)
      af[f] = *reinterpret_cast<const short8*>(&As[w * 32 + f * 16 + lr][kq * 8]);
#pragma unroll
    for (int f = 0; f < 4; ++f)
      bf[f] = *reinterpret_cast<const short8*>(&Bs[f * 16 + lr][kq * 8]);
#pragma unroll
    for (int fm = 0; fm < 2; ++fm)
#pragma unroll
      for (int fn = 0; fn < 4; ++fn)
        acc[fm][fn] = __builtin_amdgcn_mfma_f32_16x16x32_bf16(af[fm], bf[fn], acc[fm][fn], 0, 0, 0);
  }

#pragma unroll
  for (int fm = 0; fm < 2; ++fm) {
    const int rbase = m0 + w * 32 + fm * 16 + kq * 4;
#pragma unroll
    for (int fn = 0; fn < 4; ++fn) {
      const int c = n0 + fn * 16 + lr;
      const float bb = bias[c];
#pragma unroll
      for (int j = 0; j < 4; ++j)
        Out[(size_t)(rbase + j) * 1024 + c] = acc[fm][fn][j] + bb;
    }
  }
}

extern "C" void kernel_launch(void* const* d_in, const int* in_sizes, int n_in,
                              void* d_out, int out_size, void* d_ws, size_t ws_size,
                              hipStream_t stream) {
  const float* query = (const float*)d_in[0];
  const float* key   = (const float*)d_in[1];
  const float* value = (const float*)d_in[2];
  const float* q_w = (const float*)d_in[3];
  const float* q_b = (const float*)d_in[4];
  const float* k_w = (const float*)d_in[5];
  const float* k_b = (const float*)d_in[6];
  const float* v_w = (const float*)d_in[7];
  const float* v_b = (const float*)d_in[8];
  const float* o_w = (const float*)d_in[9];
  const float* o_b = (const float*)d_in[10];
  float* out = (float*)d_out;

  unsigned short* ws = (unsigned short*)d_ws;
  unsigned short* qbf = ws;                    // 2M
  unsigned short* kbf = qbf + 2097152;         // 2M
  unsigned short* vbf = kbf + 2097152;         // 2M
  unsigned short* wqb = vbf + 2097152;         // 1M
  unsigned short* wkb = wqb + 1048576;
  unsigned short* wvb = wkb + 1048576;
  unsigned short* wob = wvb + 1048576;
  unsigned short* qrope = wob + 1048576;       // 2M bf16 [2048][1024]
  unsigned short* krope = qrope + 2097152;     // 2M
  unsigned short* vTb   = krope + 2097152;     // 2M bf16 [1024][2048]
  unsigned short* ctxb  = vTb + 2097152;       // 2M
  // total ~36 MB

  cvt_all<<<10240, 256, 0, stream>>>(query, key, value, q_w, k_w, v_w, o_w,
                                     qbf, kbf, vbf, wqb, wkb, wvb, wob);
  qkv_gemm<<<dim3(48, 16), 256, 0, stream>>>(qbf, kbf, vbf, wqb, wkb, wvb,
                                             q_b, k_b, v_b, qrope, krope, vTb);
  attn_kernel<<<512, 256, 0, stream>>>(qrope, krope, vTb, ctxb);
  oproj_gemm<<<dim3(16, 16), 256, 0, stream>>>(ctxb, wob, o_b, out);
}